// Round 8
// baseline (625.798 us; speedup 1.0000x reference)
//
#include <hip/hip_runtime.h>
#include <math.h>

// SparseDiffAttn: B=1,H=12,N=2048,D=128, BM=64, top-k=192, static window [c-153,c+153),
// random keys via modern-JAX randint under jax_threefry_partitionable=True:
//   k1 = tf((0,1),(0,0)), k2 = tf((0,1),(0,1))        [fold-like split]
//   bits(k,i) = b1^b2 with (b1,b2) = tf(k,(0,i))      [partitionable random_bits]
//   offset = ((hi%100)*96 + lo%100) % 100; rnd <=> offset==0
constexpr int Hh   = 12;
constexpr int Nn   = 2048;
constexpr int Dd   = 128;
constexpr int BMq  = 64;
constexpr int QGg  = 32;            // Nn/BMq
constexpr int KSEL = 192;           // 64 * round(0.1*2048/64)
constexpr int CK   = 32;            // key chunk (k3)
constexpr int DC   = 32;            // d-chunk (k1a)
constexpr int LSTR = 132;           // padded LDS row stride (floats)
constexpr float SCALE = 0.08838834764831845f;  // 1/sqrt(128)

// persistent scratch (fully rewritten every launch before any read)
__device__ float          g_E [(size_t)Hh*Nn*Nn];   // 201 MB: exp(score), [h*2048+row][j]
__device__ float          g_lp[(size_t)Hh*Nn*16];   // per-jb partial row sums
__device__ float          g_bs[(size_t)Hh*QGg*Nn];  // colsum scores per group
__device__ unsigned short g_sel[Hh*QGg*Nn];
__device__ int            g_cnt[Hh*QGg];

__device__ __forceinline__ unsigned int rotl32(unsigned int x, int n){
  return (x << n) | (x >> (32 - n));
}

// threefry2x32, 20 rounds, arbitrary key
__device__ __forceinline__ void tf2x32(unsigned int k0, unsigned int k1,
                                       unsigned int x0, unsigned int x1,
                                       unsigned int &o0, unsigned int &o1){
  const unsigned int ks2 = 0x1BD11BDAu ^ k0 ^ k1;
  x0 += k0; x1 += k1;
  x0 += x1; x1 = rotl32(x1,13); x1 ^= x0;
  x0 += x1; x1 = rotl32(x1,15); x1 ^= x0;
  x0 += x1; x1 = rotl32(x1,26); x1 ^= x0;
  x0 += x1; x1 = rotl32(x1, 6); x1 ^= x0;
  x0 += k1; x1 += ks2 + 1u;
  x0 += x1; x1 = rotl32(x1,17); x1 ^= x0;
  x0 += x1; x1 = rotl32(x1,29); x1 ^= x0;
  x0 += x1; x1 = rotl32(x1,16); x1 ^= x0;
  x0 += x1; x1 = rotl32(x1,24); x1 ^= x0;
  x0 += ks2; x1 += k0 + 2u;
  x0 += x1; x1 = rotl32(x1,13); x1 ^= x0;
  x0 += x1; x1 = rotl32(x1,15); x1 ^= x0;
  x0 += x1; x1 = rotl32(x1,26); x1 ^= x0;
  x0 += x1; x1 = rotl32(x1, 6); x1 ^= x0;
  x0 += k0; x1 += k1 + 3u;
  x0 += x1; x1 = rotl32(x1,17); x1 ^= x0;
  x0 += x1; x1 = rotl32(x1,29); x1 ^= x0;
  x0 += x1; x1 = rotl32(x1,16); x1 ^= x0;
  x0 += x1; x1 = rotl32(x1,24); x1 ^= x0;
  x0 += k1; x1 += ks2 + 4u;
  x0 += x1; x1 = rotl32(x1,13); x1 ^= x0;
  x0 += x1; x1 = rotl32(x1,15); x1 ^= x0;
  x0 += x1; x1 = rotl32(x1,26); x1 ^= x0;
  x0 += x1; x1 = rotl32(x1, 6); x1 ^= x0;
  x0 += ks2; x1 += k0 + 5u;
  o0 = x0; o1 = x1;
}

// partitionable-threefry randint(key(1), ..., 0, 100) == 0 for flat element idx
__device__ __forceinline__ bool jax_rand01(unsigned int idx,
                                           unsigned int k1a, unsigned int k1b,
                                           unsigned int k2a, unsigned int k2b){
  unsigned int h0, h1, l0, l1;
  tf2x32(k1a, k1b, 0u, idx, h0, h1);
  tf2x32(k2a, k2b, 0u, idx, l0, l1);
  unsigned int h = h0 ^ h1;
  unsigned int l = l0 ^ l1;
  unsigned int off = ((h % 100u) * 96u + (l % 100u)) % 100u;
  return off == 0u;
}

// ---------------- Kernel 1a: one-pass E=exp(QK^T*scale) + partial row sums ----------------
__global__ __launch_bounds__(256) void k1a_scores(const float* __restrict__ Q,
                                                  const float* __restrict__ K){
  const int bid = blockIdx.x;
  const int jb = bid & 15, gp = (bid >> 4) & 15, h = bid >> 8;
  const int t = threadIdx.x, tx = t & 15, ty = t >> 4;
  __shared__ float Qt[DC][LSTR];   // transposed, pre-scaled
  __shared__ float Kt[DC][LSTR];   // transposed
  __shared__ float lsum[128][17];

  const int R0 = gp*128, J0 = jb*128;
  const float* Qb = Q + ((size_t)h*Nn + R0)*Dd;
  const float* Kb = K + ((size_t)h*Nn + J0)*Dd;

  float acc[8][8] = {};
  float4 qreg[4], kreg[4];
  #pragma unroll
  for (int it = 0; it < 4; ++it){
    int e = it*256 + t, r = e >> 3, d4 = e & 7;
    qreg[it] = ((const float4*)(Qb + (size_t)r*Dd))[d4];
    kreg[it] = ((const float4*)(Kb + (size_t)r*Dd))[d4];
  }
  for (int c = 0; c < Dd/DC; ++c){
    #pragma unroll
    for (int it = 0; it < 4; ++it){
      int e = it*256 + t, r = e >> 3, d4 = e & 7;
      float4 qv = qreg[it], kv = kreg[it];
      Qt[d4*4+0][r] = qv.x*SCALE; Qt[d4*4+1][r] = qv.y*SCALE;
      Qt[d4*4+2][r] = qv.z*SCALE; Qt[d4*4+3][r] = qv.w*SCALE;
      Kt[d4*4+0][r] = kv.x; Kt[d4*4+1][r] = kv.y;
      Kt[d4*4+2][r] = kv.z; Kt[d4*4+3][r] = kv.w;
    }
    __syncthreads();
    if (c < Dd/DC - 1){
      const int d0 = (c+1)*DC;
      #pragma unroll
      for (int it = 0; it < 4; ++it){
        int e = it*256 + t, r = e >> 3, d4 = e & 7;
        qreg[it] = ((const float4*)(Qb + (size_t)r*Dd + d0))[d4];
        kreg[it] = ((const float4*)(Kb + (size_t)r*Dd + d0))[d4];
      }
    }
    #pragma unroll 8
    for (int dd = 0; dd < DC; ++dd){
      float a[8], b[8];
      *(float4*)&a[0] = *(const float4*)&Qt[dd][ty*8];
      *(float4*)&a[4] = *(const float4*)&Qt[dd][ty*8+4];
      *(float4*)&b[0] = *(const float4*)&Kt[dd][tx*8];
      *(float4*)&b[4] = *(const float4*)&Kt[dd][tx*8+4];
      #pragma unroll
      for (int i = 0; i < 8; ++i)
        #pragma unroll
        for (int j = 0; j < 8; ++j)
          acc[i][j] += a[i]*b[j];
    }
    __syncthreads();
  }

  #pragma unroll
  for (int i = 0; i < 8; ++i){
    const int r = ty*8 + i;
    float ev[8]; float s = 0.f;
    #pragma unroll
    for (int j = 0; j < 8; ++j){ ev[j] = expf(acc[i][j]); s += ev[j]; }
    lsum[r][tx] = s;
    float4 e0, e1;
    e0.x=ev[0]; e0.y=ev[1]; e0.z=ev[2]; e0.w=ev[3];
    e1.x=ev[4]; e1.y=ev[5]; e1.z=ev[6]; e1.w=ev[7];
    float* Ep = &g_E[((size_t)h*Nn + R0 + r)*Nn + J0 + tx*8];
    *(float4*)Ep = e0;
    *(float4*)(Ep+4) = e1;
  }
  __syncthreads();
  if (t < 128){
    float s = 0.f;
    #pragma unroll
    for (int x = 0; x < 16; ++x) s += lsum[t][x];
    g_lp[((size_t)h*Nn + R0 + t)*16 + jb] = s;
  }
}

// ---------------- Kernel 2a: parallel weighted colsum bs_j = sum_r E_rj / l_r ----------------
// grid = Hh*QGg*2; block covers 1024 consecutive j; 8 independent row-loads in flight.
__global__ __launch_bounds__(256) void k2a_colsum(){
  const int bid = blockIdx.x;
  const int half = bid & 1, gg = bid >> 1;
  const int h = gg / QGg, g = gg % QGg, t = threadIdx.x;
  __shared__ float il[BMq];
  if (t < BMq){
    const float* lp = &g_lp[((size_t)h*Nn + g*BMq + t)*16];
    float s = 0.f;
    #pragma unroll
    for (int x = 0; x < 16; ++x) s += lp[x];
    il[t] = 1.0f / s;
  }
  __syncthreads();
  const int j0 = half*1024 + t*4;
  const float* Ep = &g_E[((size_t)h*Nn + (size_t)g*BMq)*Nn + j0];
  float4 s = {0.f, 0.f, 0.f, 0.f};
  for (int r = 0; r < BMq; r += 8){
    float4 e[8];
    #pragma unroll
    for (int u = 0; u < 8; ++u)
      e[u] = *(const float4*)(Ep + (size_t)(r+u)*Nn);
    #pragma unroll
    for (int u = 0; u < 8; ++u){
      float w = il[r+u];
      s.x += e[u].x*w; s.y += e[u].y*w; s.z += e[u].z*w; s.w += e[u].w*w;
    }
  }
  *(float4*)&g_bs[(size_t)gg*Nn + j0] = s;
}

// ---------------- Kernel 2b: top-k + random + static window -> compacted key list ----------------
// per-bit dedicated counters -> 1 barrier per search bit.
__global__ __launch_bounds__(256) void k2b_mask(){
  const int bid = blockIdx.x, g = bid % QGg, t = threadIdx.x;
  __shared__ float bsv[Nn];
  __shared__ int red[33];
  __shared__ int csel;
  const float* src = g_bs + (size_t)bid*Nn;
  #pragma unroll
  for (int it = 0; it < 2; ++it)
    *(float4*)&bsv[(it*256 + t)*4] = *(const float4*)&src[(it*256 + t)*4];
  if (t < 33) red[t] = 0;
  if (t == 0) csel = 0;
  __syncthreads();

  unsigned int k1a, k1b, k2a, k2b;
  tf2x32(0u, 1u, 0u, 0u, k1a, k1b);
  tf2x32(0u, 1u, 0u, 1u, k2a, k2b);

  // 192nd-largest value via bitwise binary search (values positive -> uint order)
  unsigned int prefix = 0u;
  for (int bit = 31; bit >= 0; --bit){
    unsigned int cand = prefix | (1u << bit);
    int c = 0;
    #pragma unroll
    for (int it = 0; it < 8; ++it)
      c += (__float_as_uint(bsv[it*256 + t]) >= cand) ? 1 : 0;
    #pragma unroll
    for (int off = 32; off > 0; off >>= 1) c += __shfl_down(c, off);
    if ((t & 63) == 0) atomicAdd(&red[bit], c);
    __syncthreads();
    if (red[bit] >= KSEL) prefix = cand;
  }
  {
    int cg = 0;
    #pragma unroll
    for (int it = 0; it < 8; ++it)
      cg += (__float_as_uint(bsv[it*256 + t]) > prefix) ? 1 : 0;
    #pragma unroll
    for (int off = 32; off > 0; off >>= 1) cg += __shfl_down(cg, off);
    if ((t & 63) == 0) atomicAdd(&red[32], cg);
  }
  __syncthreads();
  const int need = KSEL - red[32];   // ties taken lowest-index-first (jax top_k)

  const int lo = g*BMq + BMq/2 - 153;   // ws=int(0.15*2048)=307, ws//2=153
  const int hi = g*BMq + BMq/2 + 153;
  const int ssum = ((hi < Nn) ? hi : Nn) - ((lo > 0) ? lo : 0);
  const bool vqg = (ssum + KSEL) < Nn;  // always true at this config

  for (int it = 0; it < 8; ++it){
    int j = it*256 + t;
    unsigned int bu = __float_as_uint(bsv[j]);
    bool topk = bu > prefix;
    if (!topk && bu == prefix){
      int tr = 0;
      for (int jj = 0; jj < j; ++jj)
        tr += (__float_as_uint(bsv[jj]) == prefix) ? 1 : 0;
      topk = (tr < need);
    }
    bool rnd = jax_rand01((unsigned)(bid*Nn + j), k1a, k1b, k2a, k2b);
    bool st  = (j >= lo) && (j < hi);
    bool selb = st || ((rnd || topk) && vqg);
    if (selb){
      int slot = atomicAdd(&csel, 1);
      g_sel[(size_t)bid*Nn + slot] = (unsigned short)j;
    }
  }
  __syncthreads();
  if (t == 0) g_cnt[bid] = csel;
}

// ---------------- Kernel 3: ONE-PASS masked attention, register-prefetched gathers ------
// Block = 32 query rows x all selected keys; grid = H*QG*2. LDS 38.4 KB -> 4 blocks/CU.
// V_c loads issue before QK_c compute; K_{c+1} loads issue before PV_c compute.
__global__ __launch_bounds__(256) void k3_attn(const float* __restrict__ Q,
                                               const float* __restrict__ K,
                                               const float* __restrict__ V,
                                               const float* __restrict__ OC,
                                               float* __restrict__ out){
  const int bid = blockIdx.x;
  const int half = bid & 1;
  const int gg   = bid >> 1;           // h*QGg + g
  const int h = gg / QGg, g = gg % QGg;
  const int t = threadIdx.x;
  __shared__ float q_s[32][Dd+4];
  __shared__ float kv_s[CK][Dd+4];
  __shared__ float s_s[32][CK+1];
  __shared__ float l_s[32];
  const int c = g_cnt[gg];
  const unsigned short* sel = g_sel + (size_t)gg*Nn;

  const float* qb = Q + ((size_t)h*Nn + (size_t)g*BMq + half*32)*Dd;
  #pragma unroll
  for (int it = 0; it < 4; ++it){
    int e = it*256 + t;                 // 1024 float4s = 32 rows x 32 f4
    int row = e >> 5, c4 = e & 31;
    float4 vq = ((const float4*)qb)[e];
    float4 sv; sv.x = vq.x*SCALE; sv.y = vq.y*SCALE; sv.z = vq.z*SCALE; sv.w = vq.w*SCALE;
    *(float4*)&q_s[row][c4*4] = sv;
  }
  if (t < 32) l_s[t] = 0.0f;

  const int rt = t & 15, kcol = (t >> 4)*2;
  const int d0 = (t >> 4)*8;           // PV column group
  float acc2[2][8] = {};
  float4 kreg[4], vreg[4];

  // prefetch K chunk 0
  #pragma unroll
  for (int it = 0; it < 4; ++it){
    int e = it*256 + t, row = e >> 5, c4 = e & 31;
    int idx = row;
    int j = (idx < c) ? (int)sel[idx] : 0;
    kreg[it] = ((const float4*)(K + ((size_t)h*Nn + j)*Dd))[c4];
  }
  #pragma unroll
  for (int it = 0; it < 4; ++it){
    int e = it*256 + t, row = e >> 5, c4 = e & 31;
    *(float4*)&kv_s[row][c4*4] = kreg[it];
  }
  __syncthreads();

  for (int c0 = 0; c0 < c; c0 += CK){
    const int cc = ((c - c0) < CK) ? (c - c0) : CK;
    // issue V chunk c0 loads (consumed after QK)
    #pragma unroll
    for (int it = 0; it < 4; ++it){
      int e = it*256 + t, row = e >> 5, c4 = e & 31;
      int idx = c0 + row;
      int j = (idx < c) ? (int)sel[idx] : 0;
      vreg[it] = ((const float4*)(V + ((size_t)h*Nn + j)*Dd))[c4];
    }
    // QK on kv_s (K chunk c0): rows {rt, rt+16} x cols {kcol, kcol+1}
    float a00=0.f, a01=0.f, a10=0.f, a11=0.f;
    #pragma unroll 8
    for (int d = 0; d < Dd; d += 4){
      float4 k0 = *(const float4*)&kv_s[kcol][d];
      float4 k1 = *(const float4*)&kv_s[kcol+1][d];
      float4 q0 = *(const float4*)&q_s[rt][d];
      float4 q1 = *(const float4*)&q_s[rt+16][d];
      a00 += q0.x*k0.x + q0.y*k0.y + q0.z*k0.z + q0.w*k0.w;
      a01 += q0.x*k1.x + q0.y*k1.y + q0.z*k1.z + q0.w*k1.w;
      a10 += q1.x*k0.x + q1.y*k0.y + q1.z*k0.z + q1.w*k0.w;
      a11 += q1.x*k1.x + q1.y*k1.y + q1.z*k1.z + q1.w*k1.w;
    }
    s_s[rt   ][kcol  ] = (kcol   < cc) ? expf(a00) : 0.f;
    s_s[rt   ][kcol+1] = (kcol+1 < cc) ? expf(a01) : 0.f;
    s_s[rt+16][kcol  ] = (kcol   < cc) ? expf(a10) : 0.f;
    s_s[rt+16][kcol+1] = (kcol+1 < cc) ? expf(a11) : 0.f;
    __syncthreads();
    // write V chunk into kv_s (vmcnt wait lands here, after QK compute)
    #pragma unroll
    for (int it = 0; it < 4; ++it){
      int e = it*256 + t, row = e >> 5, c4 = e & 31;
      *(float4*)&kv_s[row][c4*4] = vreg[it];
    }
    // row-sum accumulate (l)
    if (t < 32){
      float s = 0.f;
      #pragma unroll
      for (int c2 = 0; c2 < CK; ++c2) s += s_s[t][c2];
      l_s[t] += s;
    }
    __syncthreads();
    // issue K chunk c0+CK loads (consumed after PV)
    #pragma unroll
    for (int it = 0; it < 4; ++it){
      int e = it*256 + t, row = e >> 5, c4 = e & 31;
      int idx = c0 + CK + row;
      int j = (idx < c) ? (int)sel[idx] : 0;
      kreg[it] = ((const float4*)(K + ((size_t)h*Nn + j)*Dd))[c4];
    }
    // PV: rows {rt, rt+16}, cols d0..d0+7
    for (int c2 = 0; c2 < cc; ++c2){
      float p0 = s_s[rt][c2], p1 = s_s[rt+16][c2];
      float4 va = *(const float4*)&kv_s[c2][d0];
      float4 vb = *(const float4*)&kv_s[c2][d0+4];
      acc2[0][0] += p0*va.x; acc2[0][1] += p0*va.y;
      acc2[0][2] += p0*va.z; acc2[0][3] += p0*va.w;
      acc2[0][4] += p0*vb.x; acc2[0][5] += p0*vb.y;
      acc2[0][6] += p0*vb.z; acc2[0][7] += p0*vb.w;
      acc2[1][0] += p1*va.x; acc2[1][1] += p1*va.y;
      acc2[1][2] += p1*va.z; acc2[1][3] += p1*va.w;
      acc2[1][4] += p1*vb.x; acc2[1][5] += p1*vb.y;
      acc2[1][6] += p1*vb.z; acc2[1][7] += p1*vb.w;
    }
    __syncthreads();
    // write next K chunk into kv_s
    #pragma unroll
    for (int it = 0; it < 4; ++it){
      int e = it*256 + t, row = e >> 5, c4 = e & 31;
      *(float4*)&kv_s[row][c4*4] = kreg[it];
    }
    __syncthreads();
  }

  if (t < 32) l_s[t] = 1.0f / l_s[t];
  __syncthreads();

  #pragma unroll
  for (int rr = 0; rr < 2; ++rr){
    const int r = rr*16 + rt;
    const float il = l_s[r];
    size_t o = ((size_t)h*Nn + (size_t)g*BMq + half*32 + r)*Dd + d0;
    float4 ca = *(const float4*)(OC + o);
    float4 cb = *(const float4*)(OC + o + 4);
    float4 ra, rb;
    ra.x = acc2[rr][0]*il + ca.x; ra.y = acc2[rr][1]*il + ca.y;
    ra.z = acc2[rr][2]*il + ca.z; ra.w = acc2[rr][3]*il + ca.w;
    rb.x = acc2[rr][4]*il + cb.x; rb.y = acc2[rr][5]*il + cb.y;
    rb.z = acc2[rr][6]*il + cb.z; rb.w = acc2[rr][7]*il + cb.w;
    *(float4*)(out + o)     = ra;
    *(float4*)(out + o + 4) = rb;
  }
}

extern "C" void kernel_launch(void* const* d_in, const int* in_sizes, int n_in,
                              void* d_out, int out_size, void* d_ws, size_t ws_size,
                              hipStream_t stream) {
  (void)in_sizes; (void)n_in; (void)out_size; (void)d_ws; (void)ws_size;
  const float* Q  = (const float*)d_in[0];
  const float* K  = (const float*)d_in[1];
  const float* V  = (const float*)d_in[2];
  const float* OC = (const float*)d_in[3];
  float* out = (float*)d_out;
  hipLaunchKernelGGL(k1a_scores, dim3(Hh*16*16), dim3(256), 0, stream, Q, K);
  hipLaunchKernelGGL(k2a_colsum, dim3(Hh*QGg*2), dim3(256), 0, stream);
  hipLaunchKernelGGL(k2b_mask,   dim3(Hh*QGg),   dim3(256), 0, stream);
  hipLaunchKernelGGL(k3_attn,    dim3(Hh*QGg*2), dim3(256), 0, stream, Q, K, V, OC, out);
}

// Round 9
// 563.318 us; speedup vs baseline: 1.1109x; 1.1109x over previous
//
#include <hip/hip_runtime.h>
#include <math.h>

// SparseDiffAttn: B=1,H=12,N=2048,D=128, BM=64, top-k=192, static window [c-153,c+153),
// random keys via modern-JAX randint under jax_threefry_partitionable=True:
//   k1 = tf((0,1),(0,0)), k2 = tf((0,1),(0,1))        [fold-like split]
//   bits(k,i) = b1^b2 with (b1,b2) = tf(k,(0,i))      [partitionable random_bits]
//   offset = ((hi%100)*96 + lo%100) % 100; rnd <=> offset==0
constexpr int Hh   = 12;
constexpr int Nn   = 2048;
constexpr int Dd   = 128;
constexpr int BMq  = 64;
constexpr int QGg  = 32;            // Nn/BMq
constexpr int KSEL = 192;           // 64 * round(0.1*2048/64)
constexpr int CK   = 32;            // key chunk (k3)
constexpr int DC   = 32;            // d-chunk (k1a)
constexpr int LSTR = 141;           // padded LDS row stride (floats), fits SW(127)=139
constexpr float SCALE = 0.08838834764831845f;  // 1/sqrt(128)

// skew swizzle to break 4-way LDS bank conflicts on 8-float-strided b128 reads
__device__ __forceinline__ int SW(int col){ return col + ((col >> 5) << 2); }

// persistent scratch (fully rewritten every launch before any read)
__device__ float          g_E [(size_t)Hh*Nn*Nn];   // 201 MB: exp(score), [h*2048+row][j]
__device__ float          g_lp[(size_t)Hh*Nn*16];   // per-jb partial row sums
__device__ unsigned short g_sel[Hh*QGg*Nn];
__device__ int            g_cnt[Hh*QGg];

__device__ __forceinline__ unsigned int rotl32(unsigned int x, int n){
  return (x << n) | (x >> (32 - n));
}

// threefry2x32, 20 rounds, arbitrary key
__device__ __forceinline__ void tf2x32(unsigned int k0, unsigned int k1,
                                       unsigned int x0, unsigned int x1,
                                       unsigned int &o0, unsigned int &o1){
  const unsigned int ks2 = 0x1BD11BDAu ^ k0 ^ k1;
  x0 += k0; x1 += k1;
  x0 += x1; x1 = rotl32(x1,13); x1 ^= x0;
  x0 += x1; x1 = rotl32(x1,15); x1 ^= x0;
  x0 += x1; x1 = rotl32(x1,26); x1 ^= x0;
  x0 += x1; x1 = rotl32(x1, 6); x1 ^= x0;
  x0 += k1; x1 += ks2 + 1u;
  x0 += x1; x1 = rotl32(x1,17); x1 ^= x0;
  x0 += x1; x1 = rotl32(x1,29); x1 ^= x0;
  x0 += x1; x1 = rotl32(x1,16); x1 ^= x0;
  x0 += x1; x1 = rotl32(x1,24); x1 ^= x0;
  x0 += ks2; x1 += k0 + 2u;
  x0 += x1; x1 = rotl32(x1,13); x1 ^= x0;
  x0 += x1; x1 = rotl32(x1,15); x1 ^= x0;
  x0 += x1; x1 = rotl32(x1,26); x1 ^= x0;
  x0 += x1; x1 = rotl32(x1, 6); x1 ^= x0;
  x0 += k0; x1 += k1 + 3u;
  x0 += x1; x1 = rotl32(x1,17); x1 ^= x0;
  x0 += x1; x1 = rotl32(x1,29); x1 ^= x0;
  x0 += x1; x1 = rotl32(x1,16); x1 ^= x0;
  x0 += x1; x1 = rotl32(x1,24); x1 ^= x0;
  x0 += k1; x1 += ks2 + 4u;
  x0 += x1; x1 = rotl32(x1,13); x1 ^= x0;
  x0 += x1; x1 = rotl32(x1,15); x1 ^= x0;
  x0 += x1; x1 = rotl32(x1,26); x1 ^= x0;
  x0 += x1; x1 = rotl32(x1, 6); x1 ^= x0;
  x0 += ks2; x1 += k0 + 5u;
  o0 = x0; o1 = x1;
}

// partitionable-threefry randint(key(1), ..., 0, 100) == 0 for flat element idx
__device__ __forceinline__ bool jax_rand01(unsigned int idx,
                                           unsigned int k1a, unsigned int k1b,
                                           unsigned int k2a, unsigned int k2b){
  unsigned int h0, h1, l0, l1;
  tf2x32(k1a, k1b, 0u, idx, h0, h1);
  tf2x32(k2a, k2b, 0u, idx, l0, l1);
  unsigned int h = h0 ^ h1;
  unsigned int l = l0 ^ l1;
  unsigned int off = ((h % 100u) * 96u + (l % 100u)) % 100u;
  return off == 0u;
}

// ---------------- Kernel 1a: one-pass E=exp(QK^T*scale) + partial row sums ----------------
// 128x128 tile, 8x8 micro-tile, skew-swizzled LDS (2-way conflicts only).
__global__ __launch_bounds__(256) void k1a_scores(const float* __restrict__ Q,
                                                  const float* __restrict__ K){
  const int bid = blockIdx.x;
  const int jb = bid & 15, gp = (bid >> 4) & 15, h = bid >> 8;
  const int t = threadIdx.x, tx = t & 15, ty = t >> 4;
  __shared__ float Qt[DC][LSTR];   // transposed, pre-scaled, skewed
  __shared__ float Kt[DC][LSTR];   // transposed, skewed
  __shared__ float lsum[128][17];

  const int R0 = gp*128, J0 = jb*128;
  const float* Qb = Q + ((size_t)h*Nn + R0)*Dd;
  const float* Kb = K + ((size_t)h*Nn + J0)*Dd;

  const int si = SW(ty*8);    // a-fragment base (skewed)
  const int sj = SW(tx*8);    // b-fragment base (skewed)

  float acc[8][8] = {};
  float4 qreg[4], kreg[4];
  #pragma unroll
  for (int it = 0; it < 4; ++it){
    int e = it*256 + t, r = e >> 3, d4 = e & 7;
    qreg[it] = ((const float4*)(Qb + (size_t)r*Dd))[d4];
    kreg[it] = ((const float4*)(Kb + (size_t)r*Dd))[d4];
  }
  for (int c = 0; c < Dd/DC; ++c){
    #pragma unroll
    for (int it = 0; it < 4; ++it){
      int e = it*256 + t, r = e >> 3, d4 = e & 7;
      int rs = SW(r);
      float4 qv = qreg[it], kv = kreg[it];
      Qt[d4*4+0][rs] = qv.x*SCALE; Qt[d4*4+1][rs] = qv.y*SCALE;
      Qt[d4*4+2][rs] = qv.z*SCALE; Qt[d4*4+3][rs] = qv.w*SCALE;
      Kt[d4*4+0][rs] = kv.x; Kt[d4*4+1][rs] = kv.y;
      Kt[d4*4+2][rs] = kv.z; Kt[d4*4+3][rs] = kv.w;
    }
    __syncthreads();
    if (c < Dd/DC - 1){
      const int d0 = (c+1)*DC;
      #pragma unroll
      for (int it = 0; it < 4; ++it){
        int e = it*256 + t, r = e >> 3, d4 = e & 7;
        qreg[it] = ((const float4*)(Qb + (size_t)r*Dd + d0))[d4];
        kreg[it] = ((const float4*)(Kb + (size_t)r*Dd + d0))[d4];
      }
    }
    #pragma unroll 8
    for (int dd = 0; dd < DC; ++dd){
      float a[8], b[8];
      *(float4*)&a[0] = *(const float4*)&Qt[dd][si];
      *(float4*)&a[4] = *(const float4*)&Qt[dd][si+4];
      *(float4*)&b[0] = *(const float4*)&Kt[dd][sj];
      *(float4*)&b[4] = *(const float4*)&Kt[dd][sj+4];
      #pragma unroll
      for (int i = 0; i < 8; ++i)
        #pragma unroll
        for (int j = 0; j < 8; ++j)
          acc[i][j] += a[i]*b[j];
    }
    __syncthreads();
  }

  #pragma unroll
  for (int i = 0; i < 8; ++i){
    const int r = ty*8 + i;
    float ev[8]; float s = 0.f;
    #pragma unroll
    for (int j = 0; j < 8; ++j){ ev[j] = expf(acc[i][j]); s += ev[j]; }
    lsum[r][tx] = s;
    float4 e0, e1;
    e0.x=ev[0]; e0.y=ev[1]; e0.z=ev[2]; e0.w=ev[3];
    e1.x=ev[4]; e1.y=ev[5]; e1.z=ev[6]; e1.w=ev[7];
    float* Ep = &g_E[((size_t)h*Nn + R0 + r)*Nn + J0 + tx*8];
    *(float4*)Ep = e0;
    *(float4*)(Ep+4) = e1;
  }
  __syncthreads();
  if (t < 128){
    float s = 0.f;
    #pragma unroll
    for (int x = 0; x < 16; ++x) s += lsum[t][x];
    g_lp[((size_t)h*Nn + R0 + t)*16 + jb] = s;
  }
}

// ---------------- Kernel 2: fused bs colsum + top-k + random + static -> key list ----------------
// Block (h,g): reads own 64x2048 E slab, bs in registers (8/thread), rank search from regs.
__global__ __launch_bounds__(256) void k2_mask(){
  const int bid = blockIdx.x, h = bid / QGg, g = bid % QGg, t = threadIdx.x;
  __shared__ float bsv[Nn];
  __shared__ float il[BMq];
  __shared__ int red[33];
  __shared__ int csel;
  if (t < BMq){
    const float* lp = &g_lp[((size_t)h*Nn + g*BMq + t)*16];
    float s = 0.f;
    #pragma unroll
    for (int x = 0; x < 16; ++x) s += lp[x];
    il[t] = 1.0f / s;
  }
  if (t < 33) red[t] = 0;
  if (t == 0) csel = 0;
  __syncthreads();

  // bs for this thread's 8 columns: j in {t*4..t*4+3} u {1024+t*4..+3}
  const float* Eb = &g_E[((size_t)h*Nn + (size_t)g*BMq)*Nn];
  const int ja = t*4, jb2 = 1024 + t*4;
  float4 s0 = {0.f,0.f,0.f,0.f}, s1 = {0.f,0.f,0.f,0.f};
  for (int r = 0; r < BMq; r += 8){
    float4 e0[8], e1[8];
    #pragma unroll
    for (int u = 0; u < 8; ++u){
      e0[u] = *(const float4*)(Eb + (size_t)(r+u)*Nn + ja);
      e1[u] = *(const float4*)(Eb + (size_t)(r+u)*Nn + jb2);
    }
    #pragma unroll
    for (int u = 0; u < 8; ++u){
      float w = il[r+u];
      s0.x += e0[u].x*w; s0.y += e0[u].y*w; s0.z += e0[u].z*w; s0.w += e0[u].w*w;
      s1.x += e1[u].x*w; s1.y += e1[u].y*w; s1.z += e1[u].z*w; s1.w += e1[u].w*w;
    }
  }
  *(float4*)&bsv[ja]  = s0;
  *(float4*)&bsv[jb2] = s1;
  float mine[8] = {s0.x,s0.y,s0.z,s0.w, s1.x,s1.y,s1.z,s1.w};
  __syncthreads();

  unsigned int k1a, k1b, k2a, k2b;
  tf2x32(0u, 1u, 0u, 0u, k1a, k1b);
  tf2x32(0u, 1u, 0u, 1u, k2a, k2b);

  // 192nd-largest via bitwise binary search on register values (positive -> uint order)
  unsigned int prefix = 0u;
  for (int bit = 31; bit >= 0; --bit){
    unsigned int cand = prefix | (1u << bit);
    int c = 0;
    #pragma unroll
    for (int u = 0; u < 8; ++u)
      c += (__float_as_uint(mine[u]) >= cand) ? 1 : 0;
    #pragma unroll
    for (int off = 32; off > 0; off >>= 1) c += __shfl_down(c, off);
    if ((t & 63) == 0) atomicAdd(&red[bit], c);
    __syncthreads();
    if (red[bit] >= KSEL) prefix = cand;
  }
  {
    int cg = 0;
    #pragma unroll
    for (int u = 0; u < 8; ++u)
      cg += (__float_as_uint(mine[u]) > prefix) ? 1 : 0;
    #pragma unroll
    for (int off = 32; off > 0; off >>= 1) cg += __shfl_down(cg, off);
    if ((t & 63) == 0) atomicAdd(&red[32], cg);
  }
  __syncthreads();
  const int need = KSEL - red[32];   // ties taken lowest-index-first (jax top_k)

  const int lo = g*BMq + BMq/2 - 153;   // ws=int(0.15*2048)=307, ws//2=153
  const int hi = g*BMq + BMq/2 + 153;
  const int ssum = ((hi < Nn) ? hi : Nn) - ((lo > 0) ? lo : 0);
  const bool vqg = (ssum + KSEL) < Nn;  // always true at this config

  #pragma unroll
  for (int u = 0; u < 8; ++u){
    int j = (u < 4) ? (ja + u) : (jb2 + u - 4);
    unsigned int bu = __float_as_uint(mine[u]);
    bool topk = bu > prefix;
    if (!topk && bu == prefix){
      int tr = 0;
      for (int jj = 0; jj < j; ++jj)
        tr += (__float_as_uint(bsv[jj]) == prefix) ? 1 : 0;
      topk = (tr < need);
    }
    bool rnd = jax_rand01((unsigned)(bid*Nn + j), k1a, k1b, k2a, k2b);
    bool st  = (j >= lo) && (j < hi);
    bool selb = st || ((rnd || topk) && vqg);
    if (selb){
      int slot = atomicAdd(&csel, 1);
      g_sel[(size_t)bid*Nn + slot] = (unsigned short)j;
    }
  }
  __syncthreads();
  if (t == 0) g_cnt[bid] = csel;
}

// ---------------- Kernel 3: ONE-PASS masked attention (R7 version — cache-friendly) ----------------
// Block = 32 query rows (half of a group) x all selected keys. Grid = H*QG*2 = 768.
__global__ __launch_bounds__(256) void k3_attn(const float* __restrict__ Q,
                                               const float* __restrict__ K,
                                               const float* __restrict__ V,
                                               const float* __restrict__ OC,
                                               float* __restrict__ out){
  const int bid = blockIdx.x;
  const int half = bid & 1;
  const int gg   = bid >> 1;           // h*QGg + g
  const int h = gg / QGg, g = gg % QGg;
  const int t = threadIdx.x;
  __shared__ float q_s[32][Dd+4];
  __shared__ float kv_s[CK][Dd+4];
  __shared__ float s_s[32][CK+1];
  __shared__ float l_s[32];
  const int c = g_cnt[gg];
  const unsigned short* sel = g_sel + (size_t)gg*Nn;

  const float* qb = Q + ((size_t)h*Nn + (size_t)g*BMq + half*32)*Dd;
  #pragma unroll
  for (int it = 0; it < 4; ++it){
    int e = it*256 + t;                 // 1024 float4s = 32 rows x 32 f4
    int row = e >> 5, c4 = e & 31;
    float4 vq = ((const float4*)qb)[e];
    float4 sv; sv.x = vq.x*SCALE; sv.y = vq.y*SCALE; sv.z = vq.z*SCALE; sv.w = vq.w*SCALE;
    *(float4*)&q_s[row][c4*4] = sv;
  }
  if (t < 32) l_s[t] = 0.0f;
  __syncthreads();

  const int rt = t & 15, kcol = (t >> 4)*2;
  const int d0 = (t >> 4)*8;           // PV column group
  float acc2[2][8] = {};

  for (int c0 = 0; c0 < c; c0 += CK){
    const int cc = ((c - c0) < CK) ? (c - c0) : CK;
    // gather K chunk
    #pragma unroll
    for (int it = 0; it < 4; ++it){
      int e = it*256 + t, row = e >> 5, c4 = e & 31;
      int j = (row < cc) ? (int)sel[c0 + row] : 0;
      *(float4*)&kv_s[row][c4*4] = ((const float4*)(K + ((size_t)h*Nn + j)*Dd))[c4];
    }
    __syncthreads();
    // scores: rows {rt, rt+16} x cols {kcol, kcol+1}
    float a00=0.f, a01=0.f, a10=0.f, a11=0.f;
    #pragma unroll 8
    for (int d = 0; d < Dd; d += 4){
      float4 k0 = *(const float4*)&kv_s[kcol][d];
      float4 k1 = *(const float4*)&kv_s[kcol+1][d];
      float4 q0 = *(const float4*)&q_s[rt][d];
      float4 q1 = *(const float4*)&q_s[rt+16][d];
      a00 += q0.x*k0.x + q0.y*k0.y + q0.z*k0.z + q0.w*k0.w;
      a01 += q0.x*k1.x + q0.y*k1.y + q0.z*k1.z + q0.w*k1.w;
      a10 += q1.x*k0.x + q1.y*k0.y + q1.z*k0.z + q1.w*k0.w;
      a11 += q1.x*k1.x + q1.y*k1.y + q1.z*k1.z + q1.w*k1.w;
    }
    s_s[rt   ][kcol  ] = (kcol   < cc) ? expf(a00) : 0.f;
    s_s[rt   ][kcol+1] = (kcol+1 < cc) ? expf(a01) : 0.f;
    s_s[rt+16][kcol  ] = (kcol   < cc) ? expf(a10) : 0.f;
    s_s[rt+16][kcol+1] = (kcol+1 < cc) ? expf(a11) : 0.f;
    __syncthreads();
    // row-sum accumulate (l)
    if (t < 32){
      float s = 0.f;
      #pragma unroll
      for (int c2 = 0; c2 < CK; ++c2) s += s_s[t][c2];
      l_s[t] += s;
    }
    // gather V chunk (overwrites kv_s; QK readers already past barrier)
    #pragma unroll
    for (int it = 0; it < 4; ++it){
      int e = it*256 + t, row = e >> 5, c4 = e & 31;
      int j = (row < cc) ? (int)sel[c0 + row] : 0;
      *(float4*)&kv_s[row][c4*4] = ((const float4*)(V + ((size_t)h*Nn + j)*Dd))[c4];
    }
    __syncthreads();
    // PV: rows {rt, rt+16}, cols d0..d0+7
    for (int c2 = 0; c2 < cc; ++c2){
      float p0 = s_s[rt][c2], p1 = s_s[rt+16][c2];
      float4 va = *(const float4*)&kv_s[c2][d0];
      float4 vb = *(const float4*)&kv_s[c2][d0+4];
      acc2[0][0] += p0*va.x; acc2[0][1] += p0*va.y;
      acc2[0][2] += p0*va.z; acc2[0][3] += p0*va.w;
      acc2[0][4] += p0*vb.x; acc2[0][5] += p0*vb.y;
      acc2[0][6] += p0*vb.z; acc2[0][7] += p0*vb.w;
      acc2[1][0] += p1*va.x; acc2[1][1] += p1*va.y;
      acc2[1][2] += p1*va.z; acc2[1][3] += p1*va.w;
      acc2[1][4] += p1*vb.x; acc2[1][5] += p1*vb.y;
      acc2[1][6] += p1*vb.z; acc2[1][7] += p1*vb.w;
    }
    __syncthreads();
  }

  if (t < 32) l_s[t] = 1.0f / l_s[t];
  __syncthreads();

  #pragma unroll
  for (int rr = 0; rr < 2; ++rr){
    const int r = rr*16 + rt;
    const float il = l_s[r];
    size_t o = ((size_t)h*Nn + (size_t)g*BMq + half*32 + r)*Dd + d0;
    float4 ca = *(const float4*)(OC + o);
    float4 cb = *(const float4*)(OC + o + 4);
    float4 ra, rb;
    ra.x = acc2[rr][0]*il + ca.x; ra.y = acc2[rr][1]*il + ca.y;
    ra.z = acc2[rr][2]*il + ca.z; ra.w = acc2[rr][3]*il + ca.w;
    rb.x = acc2[rr][4]*il + cb.x; rb.y = acc2[rr][5]*il + cb.y;
    rb.z = acc2[rr][6]*il + cb.z; rb.w = acc2[rr][7]*il + cb.w;
    *(float4*)(out + o)     = ra;
    *(float4*)(out + o + 4) = rb;
  }
}

extern "C" void kernel_launch(void* const* d_in, const int* in_sizes, int n_in,
                              void* d_out, int out_size, void* d_ws, size_t ws_size,
                              hipStream_t stream) {
  (void)in_sizes; (void)n_in; (void)out_size; (void)d_ws; (void)ws_size;
  const float* Q  = (const float*)d_in[0];
  const float* K  = (const float*)d_in[1];
  const float* V  = (const float*)d_in[2];
  const float* OC = (const float*)d_in[3];
  float* out = (float*)d_out;
  hipLaunchKernelGGL(k1a_scores, dim3(Hh*16*16), dim3(256), 0, stream, Q, K);
  hipLaunchKernelGGL(k2_mask,    dim3(Hh*QGg),   dim3(256), 0, stream);
  hipLaunchKernelGGL(k3_attn,    dim3(Hh*QGg*2), dim3(256), 0, stream, Q, K, V, OC, out);
}

// Round 11
// 542.954 us; speedup vs baseline: 1.1526x; 1.0375x over previous
//
#include <hip/hip_runtime.h>
#include <math.h>

// SparseDiffAttn: B=1,H=12,N=2048,D=128, BM=64, top-k=192, static window [c-153,c+153),
// random keys via modern-JAX randint under jax_threefry_partitionable=True:
//   k1 = tf((0,1),(0,0)), k2 = tf((0,1),(0,1))        [fold-like split]
//   bits(k,i) = b1^b2 with (b1,b2) = tf(k,(0,i))      [partitionable random_bits]
//   offset = ((hi%100)*96 + lo%100) % 100; rnd <=> offset==0
// PRECISION NOTE: selection (bs ranking) is robust to ~1e-6 rel perturbation
// (R1==R2 fp32 vs fp64 masks identical) but NOT to fp16-E (~1e-4): R10 failed.
// E stays fp32; __expf (~5e-7) is inside the certified band.
constexpr int Hh   = 12;
constexpr int Nn   = 2048;
constexpr int Dd   = 128;
constexpr int BMq  = 64;
constexpr int QGg  = 32;            // Nn/BMq
constexpr int KSEL = 192;           // 64 * round(0.1*2048/64)
constexpr int CK   = 32;            // key chunk (k3)
constexpr int DC   = 32;            // d-chunk (k1a)
constexpr int LSTR = 132;           // padded LDS row stride (floats), 16B-aligned
constexpr float SCALE = 0.08838834764831845f;  // 1/sqrt(128)

// persistent scratch (fully rewritten every launch before any read)
__device__ float          g_E [(size_t)Hh*Nn*Nn];   // 201 MB: fp32 exp(score)
__device__ float          g_lp[(size_t)Hh*Nn*16];   // per-jb partial row sums
__device__ unsigned short g_sel[Hh*QGg*Nn];
__device__ int            g_cnt[Hh*QGg];

__device__ __forceinline__ unsigned int rotl32(unsigned int x, int n){
  return (x << n) | (x >> (32 - n));
}

// threefry2x32, 20 rounds, arbitrary key
__device__ __forceinline__ void tf2x32(unsigned int k0, unsigned int k1,
                                       unsigned int x0, unsigned int x1,
                                       unsigned int &o0, unsigned int &o1){
  const unsigned int ks2 = 0x1BD11BDAu ^ k0 ^ k1;
  x0 += k0; x1 += k1;
  x0 += x1; x1 = rotl32(x1,13); x1 ^= x0;
  x0 += x1; x1 = rotl32(x1,15); x1 ^= x0;
  x0 += x1; x1 = rotl32(x1,26); x1 ^= x0;
  x0 += x1; x1 = rotl32(x1, 6); x1 ^= x0;
  x0 += k1; x1 += ks2 + 1u;
  x0 += x1; x1 = rotl32(x1,17); x1 ^= x0;
  x0 += x1; x1 = rotl32(x1,29); x1 ^= x0;
  x0 += x1; x1 = rotl32(x1,16); x1 ^= x0;
  x0 += x1; x1 = rotl32(x1,24); x1 ^= x0;
  x0 += ks2; x1 += k0 + 2u;
  x0 += x1; x1 = rotl32(x1,13); x1 ^= x0;
  x0 += x1; x1 = rotl32(x1,15); x1 ^= x0;
  x0 += x1; x1 = rotl32(x1,26); x1 ^= x0;
  x0 += x1; x1 = rotl32(x1, 6); x1 ^= x0;
  x0 += k0; x1 += k1 + 3u;
  x0 += x1; x1 = rotl32(x1,17); x1 ^= x0;
  x0 += x1; x1 = rotl32(x1,29); x1 ^= x0;
  x0 += x1; x1 = rotl32(x1,16); x1 ^= x0;
  x0 += x1; x1 = rotl32(x1,24); x1 ^= x0;
  x0 += k1; x1 += ks2 + 4u;
  x0 += x1; x1 = rotl32(x1,13); x1 ^= x0;
  x0 += x1; x1 = rotl32(x1,15); x1 ^= x0;
  x0 += x1; x1 = rotl32(x1,26); x1 ^= x0;
  x0 += x1; x1 = rotl32(x1, 6); x1 ^= x0;
  x0 += ks2; x1 += k0 + 5u;
  o0 = x0; o1 = x1;
}

// partitionable-threefry randint(key(1), ..., 0, 100) == 0 for flat element idx
__device__ __forceinline__ bool jax_rand01(unsigned int idx,
                                           unsigned int k1a, unsigned int k1b,
                                           unsigned int k2a, unsigned int k2b){
  unsigned int h0, h1, l0, l1;
  tf2x32(k1a, k1b, 0u, idx, h0, h1);
  tf2x32(k2a, k2b, 0u, idx, l0, l1);
  unsigned int h = h0 ^ h1;
  unsigned int l = l0 ^ l1;
  unsigned int off = ((h % 100u) * 96u + (l % 100u)) % 100u;
  return off == 0u;
}

// ---------------- Kernel 1a: one-pass E=__expf(QK^T*scale) + partial row sums ----------------
__global__ __launch_bounds__(256) void k1a_scores(const float* __restrict__ Q,
                                                  const float* __restrict__ K){
  const int bid = blockIdx.x;
  const int jb = bid & 15, gp = (bid >> 4) & 15, h = bid >> 8;
  const int t = threadIdx.x, tx = t & 15, ty = t >> 4;
  __shared__ float Qt[DC][LSTR];   // transposed, pre-scaled
  __shared__ float Kt[DC][LSTR];   // transposed
  __shared__ float lsum[128][17];

  const int R0 = gp*128, J0 = jb*128;
  const float* Qb = Q + ((size_t)h*Nn + R0)*Dd;
  const float* Kb = K + ((size_t)h*Nn + J0)*Dd;

  float acc[8][8] = {};
  float4 qreg[4], kreg[4];
  #pragma unroll
  for (int it = 0; it < 4; ++it){
    int e = it*256 + t, r = e >> 3, d4 = e & 7;
    qreg[it] = ((const float4*)(Qb + (size_t)r*Dd))[d4];
    kreg[it] = ((const float4*)(Kb + (size_t)r*Dd))[d4];
  }
  for (int c = 0; c < Dd/DC; ++c){
    #pragma unroll
    for (int it = 0; it < 4; ++it){
      int e = it*256 + t, r = e >> 3, d4 = e & 7;
      float4 qv = qreg[it], kv = kreg[it];
      Qt[d4*4+0][r] = qv.x*SCALE; Qt[d4*4+1][r] = qv.y*SCALE;
      Qt[d4*4+2][r] = qv.z*SCALE; Qt[d4*4+3][r] = qv.w*SCALE;
      Kt[d4*4+0][r] = kv.x; Kt[d4*4+1][r] = kv.y;
      Kt[d4*4+2][r] = kv.z; Kt[d4*4+3][r] = kv.w;
    }
    __syncthreads();
    if (c < Dd/DC - 1){
      const int d0 = (c+1)*DC;
      #pragma unroll
      for (int it = 0; it < 4; ++it){
        int e = it*256 + t, r = e >> 3, d4 = e & 7;
        qreg[it] = ((const float4*)(Qb + (size_t)r*Dd + d0))[d4];
        kreg[it] = ((const float4*)(Kb + (size_t)r*Dd + d0))[d4];
      }
    }
    #pragma unroll 8
    for (int dd = 0; dd < DC; ++dd){
      float a[8], b[8];
      *(float4*)&a[0] = *(const float4*)&Qt[dd][ty*8];
      *(float4*)&a[4] = *(const float4*)&Qt[dd][ty*8+4];
      *(float4*)&b[0] = *(const float4*)&Kt[dd][tx*8];
      *(float4*)&b[4] = *(const float4*)&Kt[dd][tx*8+4];
      #pragma unroll
      for (int i = 0; i < 8; ++i)
        #pragma unroll
        for (int j = 0; j < 8; ++j)
          acc[i][j] += a[i]*b[j];
    }
    __syncthreads();
  }

  #pragma unroll
  for (int i = 0; i < 8; ++i){
    const int r = ty*8 + i;
    float ev[8]; float s = 0.f;
    #pragma unroll
    for (int j = 0; j < 8; ++j){ ev[j] = __expf(acc[i][j]); s += ev[j]; }
    lsum[r][tx] = s;
    float4 e0, e1;
    e0.x=ev[0]; e0.y=ev[1]; e0.z=ev[2]; e0.w=ev[3];
    e1.x=ev[4]; e1.y=ev[5]; e1.z=ev[6]; e1.w=ev[7];
    float* Ep = &g_E[((size_t)h*Nn + R0 + r)*Nn + J0 + tx*8];
    *(float4*)Ep = e0;
    *(float4*)(Ep+4) = e1;
  }
  __syncthreads();
  if (t < 128){
    float s = 0.f;
    #pragma unroll
    for (int x = 0; x < 16; ++x) s += lsum[t][x];
    g_lp[((size_t)h*Nn + R0 + t)*16 + jb] = s;
  }
}

// ---------------- Kernel 2: fused bs colsum + top-k + random + static -> key list ----------------
__global__ __launch_bounds__(256) void k2_mask(){
  const int bid = blockIdx.x, h = bid / QGg, g = bid % QGg, t = threadIdx.x;
  __shared__ float bsv[Nn];
  __shared__ float il[BMq];
  __shared__ int red[33];
  __shared__ int csel;
  if (t < BMq){
    const float* lp = &g_lp[((size_t)h*Nn + g*BMq + t)*16];
    float s = 0.f;
    #pragma unroll
    for (int x = 0; x < 16; ++x) s += lp[x];
    il[t] = 1.0f / s;
  }
  if (t < 33) red[t] = 0;
  if (t == 0) csel = 0;
  __syncthreads();

  // bs for this thread's 8 columns: j in {t*4..t*4+3} u {1024+t*4..+3}
  const float* Eb = &g_E[((size_t)h*Nn + (size_t)g*BMq)*Nn];
  const int ja = t*4, jb2 = 1024 + t*4;
  float4 s0 = {0.f,0.f,0.f,0.f}, s1 = {0.f,0.f,0.f,0.f};
  for (int r = 0; r < BMq; r += 8){
    float4 e0[8], e1[8];
    #pragma unroll
    for (int u = 0; u < 8; ++u){
      e0[u] = *(const float4*)(Eb + (size_t)(r+u)*Nn + ja);
      e1[u] = *(const float4*)(Eb + (size_t)(r+u)*Nn + jb2);
    }
    #pragma unroll
    for (int u = 0; u < 8; ++u){
      float w = il[r+u];
      s0.x += e0[u].x*w; s0.y += e0[u].y*w; s0.z += e0[u].z*w; s0.w += e0[u].w*w;
      s1.x += e1[u].x*w; s1.y += e1[u].y*w; s1.z += e1[u].z*w; s1.w += e1[u].w*w;
    }
  }
  *(float4*)&bsv[ja]  = s0;
  *(float4*)&bsv[jb2] = s1;
  float mine[8] = {s0.x,s0.y,s0.z,s0.w, s1.x,s1.y,s1.z,s1.w};
  __syncthreads();

  unsigned int k1a, k1b, k2a, k2b;
  tf2x32(0u, 1u, 0u, 0u, k1a, k1b);
  tf2x32(0u, 1u, 0u, 1u, k2a, k2b);

  // 192nd-largest via bitwise binary search on register values (positive -> uint order)
  unsigned int prefix = 0u;
  for (int bit = 31; bit >= 0; --bit){
    unsigned int cand = prefix | (1u << bit);
    int c = 0;
    #pragma unroll
    for (int u = 0; u < 8; ++u)
      c += (__float_as_uint(mine[u]) >= cand) ? 1 : 0;
    #pragma unroll
    for (int off = 32; off > 0; off >>= 1) c += __shfl_down(c, off);
    if ((t & 63) == 0) atomicAdd(&red[bit], c);
    __syncthreads();
    if (red[bit] >= KSEL) prefix = cand;
  }
  {
    int cg = 0;
    #pragma unroll
    for (int u = 0; u < 8; ++u)
      cg += (__float_as_uint(mine[u]) > prefix) ? 1 : 0;
    #pragma unroll
    for (int off = 32; off > 0; off >>= 1) cg += __shfl_down(cg, off);
    if ((t & 63) == 0) atomicAdd(&red[32], cg);
  }
  __syncthreads();
  const int need = KSEL - red[32];   // ties taken lowest-index-first (jax top_k)

  const int lo = g*BMq + BMq/2 - 153;   // ws=int(0.15*2048)=307, ws//2=153
  const int hi = g*BMq + BMq/2 + 153;
  const int ssum = ((hi < Nn) ? hi : Nn) - ((lo > 0) ? lo : 0);
  const bool vqg = (ssum + KSEL) < Nn;  // always true at this config

  #pragma unroll
  for (int u = 0; u < 8; ++u){
    int j = (u < 4) ? (ja + u) : (jb2 + u - 4);
    unsigned int bu = __float_as_uint(mine[u]);
    bool topk = bu > prefix;
    if (!topk && bu == prefix){
      int tr = 0;
      for (int jj = 0; jj < j; ++jj)
        tr += (__float_as_uint(bsv[jj]) == prefix) ? 1 : 0;
      topk = (tr < need);
    }
    bool rnd = jax_rand01((unsigned)(bid*Nn + j), k1a, k1b, k2a, k2b);
    bool st  = (j >= lo) && (j < hi);
    bool selb = st || ((rnd || topk) && vqg);
    if (selb){
      int slot = atomicAdd(&csel, 1);
      g_sel[(size_t)bid*Nn + slot] = (unsigned short)j;
    }
  }
  __syncthreads();
  if (t == 0) g_cnt[bid] = csel;
}

// ---------------- Kernel 3: ONE-PASS masked attention (cache-friendly structure) ----------------
// Block = 32 query rows (half of a group) x all selected keys. Grid = H*QG*2 = 768.
__global__ __launch_bounds__(256) void k3_attn(const float* __restrict__ Q,
                                               const float* __restrict__ K,
                                               const float* __restrict__ V,
                                               const float* __restrict__ OC,
                                               float* __restrict__ out){
  const int bid = blockIdx.x;
  const int half = bid & 1;
  const int gg   = bid >> 1;           // h*QGg + g
  const int h = gg / QGg, g = gg % QGg;
  const int t = threadIdx.x;
  __shared__ float q_s[32][Dd+4];
  __shared__ float kv_s[CK][Dd+4];
  __shared__ float s_s[32][CK+1];
  __shared__ float l_s[32];
  const int c = g_cnt[gg];
  const unsigned short* sel = g_sel + (size_t)gg*Nn;

  const float* qb = Q + ((size_t)h*Nn + (size_t)g*BMq + half*32)*Dd;
  #pragma unroll
  for (int it = 0; it < 4; ++it){
    int e = it*256 + t;                 // 1024 float4s = 32 rows x 32 f4
    int row = e >> 5, c4 = e & 31;
    float4 vq = ((const float4*)qb)[e];
    float4 sv; sv.x = vq.x*SCALE; sv.y = vq.y*SCALE; sv.z = vq.z*SCALE; sv.w = vq.w*SCALE;
    *(float4*)&q_s[row][c4*4] = sv;
  }
  if (t < 32) l_s[t] = 0.0f;
  __syncthreads();

  const int rt = t & 15, kcol = (t >> 4)*2;
  const int d0 = (t >> 4)*8;           // PV column group
  float acc2[2][8] = {};

  for (int c0 = 0; c0 < c; c0 += CK){
    const int cc = ((c - c0) < CK) ? (c - c0) : CK;
    // gather K chunk
    #pragma unroll
    for (int it = 0; it < 4; ++it){
      int e = it*256 + t, row = e >> 5, c4 = e & 31;
      int j = (row < cc) ? (int)sel[c0 + row] : 0;
      *(float4*)&kv_s[row][c4*4] = ((const float4*)(K + ((size_t)h*Nn + j)*Dd))[c4];
    }
    __syncthreads();
    // scores: rows {rt, rt+16} x cols {kcol, kcol+1}
    float a00=0.f, a01=0.f, a10=0.f, a11=0.f;
    #pragma unroll 8
    for (int d = 0; d < Dd; d += 4){
      float4 k0 = *(const float4*)&kv_s[kcol][d];
      float4 k1 = *(const float4*)&kv_s[kcol+1][d];
      float4 q0 = *(const float4*)&q_s[rt][d];
      float4 q1 = *(const float4*)&q_s[rt+16][d];
      a00 += q0.x*k0.x + q0.y*k0.y + q0.z*k0.z + q0.w*k0.w;
      a01 += q0.x*k1.x + q0.y*k1.y + q0.z*k1.z + q0.w*k1.w;
      a10 += q1.x*k0.x + q1.y*k0.y + q1.z*k0.z + q1.w*k0.w;
      a11 += q1.x*k1.x + q1.y*k1.y + q1.z*k1.z + q1.w*k1.w;
    }
    s_s[rt   ][kcol  ] = (kcol   < cc) ? __expf(a00) : 0.f;
    s_s[rt   ][kcol+1] = (kcol+1 < cc) ? __expf(a01) : 0.f;
    s_s[rt+16][kcol  ] = (kcol   < cc) ? __expf(a10) : 0.f;
    s_s[rt+16][kcol+1] = (kcol+1 < cc) ? __expf(a11) : 0.f;
    __syncthreads();
    // row-sum accumulate (l)
    if (t < 32){
      float s = 0.f;
      #pragma unroll
      for (int c2 = 0; c2 < CK; ++c2) s += s_s[t][c2];
      l_s[t] += s;
    }
    // gather V chunk (overwrites kv_s; QK readers already past barrier)
    #pragma unroll
    for (int it = 0; it < 4; ++it){
      int e = it*256 + t, row = e >> 5, c4 = e & 31;
      int j = (row < cc) ? (int)sel[c0 + row] : 0;
      *(float4*)&kv_s[row][c4*4] = ((const float4*)(V + ((size_t)h*Nn + j)*Dd))[c4];
    }
    __syncthreads();
    // PV: rows {rt, rt+16}, cols d0..d0+7
    for (int c2 = 0; c2 < cc; ++c2){
      float p0 = s_s[rt][c2], p1 = s_s[rt+16][c2];
      float4 va = *(const float4*)&kv_s[c2][d0];
      float4 vb = *(const float4*)&kv_s[c2][d0+4];
      acc2[0][0] += p0*va.x; acc2[0][1] += p0*va.y;
      acc2[0][2] += p0*va.z; acc2[0][3] += p0*va.w;
      acc2[0][4] += p0*vb.x; acc2[0][5] += p0*vb.y;
      acc2[0][6] += p0*vb.z; acc2[0][7] += p0*vb.w;
      acc2[1][0] += p1*va.x; acc2[1][1] += p1*va.y;
      acc2[1][2] += p1*va.z; acc2[1][3] += p1*va.w;
      acc2[1][4] += p1*vb.x; acc2[1][5] += p1*vb.y;
      acc2[1][6] += p1*vb.z; acc2[1][7] += p1*vb.w;
    }
    __syncthreads();
  }

  if (t < 32) l_s[t] = 1.0f / l_s[t];
  __syncthreads();

  #pragma unroll
  for (int rr = 0; rr < 2; ++rr){
    const int r = rr*16 + rt;
    const float il = l_s[r];
    size_t o = ((size_t)h*Nn + (size_t)g*BMq + half*32 + r)*Dd + d0;
    float4 ca = *(const float4*)(OC + o);
    float4 cb = *(const float4*)(OC + o + 4);
    float4 ra, rb;
    ra.x = acc2[rr][0]*il + ca.x; ra.y = acc2[rr][1]*il + ca.y;
    ra.z = acc2[rr][2]*il + ca.z; ra.w = acc2[rr][3]*il + ca.w;
    rb.x = acc2[rr][4]*il + cb.x; rb.y = acc2[rr][5]*il + cb.y;
    rb.z = acc2[rr][6]*il + cb.z; rb.w = acc2[rr][7]*il + cb.w;
    *(float4*)(out + o)     = ra;
    *(float4*)(out + o + 4) = rb;
  }
}

extern "C" void kernel_launch(void* const* d_in, const int* in_sizes, int n_in,
                              void* d_out, int out_size, void* d_ws, size_t ws_size,
                              hipStream_t stream) {
  (void)in_sizes; (void)n_in; (void)out_size; (void)d_ws; (void)ws_size;
  const float* Q  = (const float*)d_in[0];
  const float* K  = (const float*)d_in[1];
  const float* V  = (const float*)d_in[2];
  const float* OC = (const float*)d_in[3];
  float* out = (float*)d_out;
  hipLaunchKernelGGL(k1a_scores, dim3(Hh*16*16), dim3(256), 0, stream, Q, K);
  hipLaunchKernelGGL(k2_mask,    dim3(Hh*QGg),   dim3(256), 0, stream);
  hipLaunchKernelGGL(k3_attn,    dim3(Hh*QGg*2), dim3(256), 0, stream, Q, K, V, OC, out);
}